// Round 9
// baseline (172.660 us; speedup 1.0000x reference)
//
#include <hip/hip_runtime.h>

typedef unsigned short u16;
typedef __bf16 bf16x8 __attribute__((ext_vector_type(8)));
typedef float f32x4 __attribute__((ext_vector_type(4)));

#define AS1 __attribute__((address_space(1)))
#define AS3 __attribute__((address_space(3)))

// ---- fp32 -> bf16 (RNE) ----
__device__ inline u16 f2bf(float f) {
  union { float f; unsigned u; } a; a.f = f;
  unsigned u = a.u;
  return (u16)((u + 0x7fffu + ((u >> 16) & 1u)) >> 16);
}

// ---- all fp32 -> bf16 converts in one dispatch ----
__global__ __launch_bounds__(256) void cvt_all_kernel(
    const float* __restrict__ x, const float* __restrict__ wq,
    const float* __restrict__ wk, const float* __restrict__ wv,
    u16* __restrict__ xb, u16* __restrict__ wqb,
    u16* __restrict__ wkb, u16* __restrict__ wvb) {
  int bid = blockIdx.x;
  const float* in; u16* out;
  if (bid < 8192) { in = x; out = xb; }
  else if (bid < 9216) { in = wq; out = wqb; bid -= 8192; }
  else if (bid < 10240) { in = wk; out = wkb; bid -= 9216; }
  else { in = wv; out = wvb; bid -= 10240; }
  size_t i = ((size_t)bid * 256 + threadIdx.x) * 4;
  float4 v = *(const float4*)(in + i);
  ushort4 o;
  o.x = f2bf(v.x); o.y = f2bf(v.y); o.z = f2bf(v.z); o.w = f2bf(v.w);
  *(ushort4*)(out + i) = o;
}

// ============================================================================
// 256xBN 8-wave GEMM core, 4-phase dead-region schedule: C = A @ B^T.
//   BN=256: wave tile 128x64, 16 MFMA/phase; BN=128: wave tile 128x32, 8/phase.
//   RAW s_barrier only; counted vmcnt (never drains the prefetch queue).
//   T2 swizzle: 16B slot ^= (row&7) on both staged source and ds_read.
//   (correctness + ~905 TF/block @K=1024 proven rounds 3-8)
// ============================================================================
template <typename CT, int BN>
__device__ __forceinline__ void gemm_core(
    u16* __restrict__ lds,
    const u16* __restrict__ A, const u16* __restrict__ B, CT* __restrict__ C,
    int nt, int lda, int ldb, int ldc, int m0, int n0) {
  constexpr int ABUF = 16384;      // 256 rows x 64 u16 per A buffer
  constexpr int BBUF = BN * 64;
  constexpr int BSW = BN / 64;     // B staging sweeps per tile (4 or 2)
  constexpr int NI = BN / 64;      // n-frags per wave

  const int tid = threadIdx.x;
  const int ln = tid & 63, wv = tid >> 6;
  const int wr = wv >> 2, wc = wv & 3;  // 2 x 4 wave grid

  auto sweep = [&](const u16* src, int ld, int t, int s, int base) {
    const int c = s * 512 + tid;
    const int row = c >> 3, slot = c & 7;
    const int col = (slot ^ (row & 7)) * 8;
    __builtin_amdgcn_global_load_lds(
        (const AS1 void*)(src + (size_t)row * ld + (size_t)t * 64 + col),
        (AS3 void*)(&lds[base + c * 8]), 16, 0, 0);
  };

  f32x4 acc[8][NI] = {};

  // prologue: tiles 0 and 1 fully staged
#pragma unroll
  for (int s = 0; s < BSW; ++s) sweep(B, ldb, 0, s, 2 * ABUF);
#pragma unroll
  for (int s = 0; s < 4; ++s) sweep(A, lda, 0, s, 0);
  if (nt > 1) {
#pragma unroll
    for (int s = 0; s < BSW; ++s) sweep(B, ldb, 1, s, 2 * ABUF + BBUF);
#pragma unroll
    for (int s = 0; s < 4; ++s) sweep(A, lda, 1, s, ABUF);
    if constexpr (BSW == 4) asm volatile("s_waitcnt vmcnt(8)" ::: "memory");
    else                    asm volatile("s_waitcnt vmcnt(6)" ::: "memory");
  } else {
    asm volatile("s_waitcnt vmcnt(0)" ::: "memory");
  }
  __builtin_amdgcn_s_barrier();

  for (int t = 0; t < nt; ++t) {
    const int p = t & 1;
    const u16* La = &lds[p * ABUF];
    const u16* Lb = &lds[2 * ABUF + p * BBUF];
    bf16x8 bfr[NI][2];
#pragma unroll
    for (int q = 0; q < 4; ++q) {
      if (q == 0) {
        __builtin_amdgcn_sched_barrier(0);  // pin reads below publishing barrier
#pragma unroll
        for (int ni = 0; ni < NI; ++ni)
#pragma unroll
          for (int ks = 0; ks < 2; ++ks) {
            const int row = wc * (BN / 4) + ni * 16 + (ln & 15);
            const int kc = ks * 4 + (ln >> 4);
            bfr[ni][ks] = *(const bf16x8*)&Lb[row * 64 + ((kc ^ (row & 7)) << 3)];
          }
      }
      bf16x8 afr[2][2];
#pragma unroll
      for (int mi = 0; mi < 2; ++mi)
#pragma unroll
        for (int ks = 0; ks < 2; ++ks) {
          const int row = wr * 128 + (q * 2 + mi) * 16 + (ln & 15);
          const int kc = ks * 4 + (ln >> 4);
          afr[mi][ks] = *(const bf16x8*)&La[row * 64 + ((kc ^ (row & 7)) << 3)];
        }
      // dead-region staging
      if (q == 0)      { if (t >= 1 && t + 1 < nt) { sweep(A, lda, t + 1, 0, (p ^ 1) * ABUF); sweep(A, lda, t + 1, 1, (p ^ 1) * ABUF); } }
      else if (q == 1) { if (t >= 1 && t + 1 < nt) { sweep(A, lda, t + 1, 2, (p ^ 1) * ABUF); sweep(A, lda, t + 1, 3, (p ^ 1) * ABUF); } }
      else if (q == 2) { if (t + 2 < nt) { sweep(B, ldb, t + 2, 0, 2 * ABUF + p * BBUF); if (BSW == 4) sweep(B, ldb, t + 2, 1, 2 * ABUF + p * BBUF); } }
      else             { if (t + 2 < nt) { if (BSW == 4) { sweep(B, ldb, t + 2, 2, 2 * ABUF + p * BBUF); sweep(B, ldb, t + 2, 3, 2 * ABUF + p * BBUF); } else { sweep(B, ldb, t + 2, 1, 2 * ABUF + p * BBUF); } } }

      __builtin_amdgcn_s_barrier();
      __builtin_amdgcn_s_setprio(1);
#pragma unroll
      for (int mi = 0; mi < 2; ++mi)
#pragma unroll
        for (int ni = 0; ni < NI; ++ni)
#pragma unroll
          for (int ks = 0; ks < 2; ++ks)
            acc[q * 2 + mi][ni] = __builtin_amdgcn_mfma_f32_16x16x32_bf16(
                afr[mi][ks], bfr[ni][ks], acc[q * 2 + mi][ni], 0, 0, 0);
      __builtin_amdgcn_s_setprio(0);
      if (q == 3) {
        if (t + 2 < nt) {
          if constexpr (BSW == 4) asm volatile("s_waitcnt vmcnt(4)" ::: "memory");
          else                    asm volatile("s_waitcnt vmcnt(2)" ::: "memory");
        } else if (t + 1 < nt) {
          asm volatile("s_waitcnt vmcnt(0)" ::: "memory");
        }
      }
      __builtin_amdgcn_s_barrier();
    }
  }

  // epilogue: D col = lane&15 (n), row = (lane>>4)*4 + reg (m)
#pragma unroll
  for (int mi = 0; mi < 8; ++mi) {
    const int rbase = m0 + wr * 128 + mi * 16 + (ln >> 4) * 4;
#pragma unroll
    for (int ni = 0; ni < NI; ++ni) {
      const int col = n0 + wc * (BN / 4) + ni * 16 + (ln & 15);
#pragma unroll
      for (int r = 0; r < 4; ++r) {
        const float v = acc[mi][ni][r];
        CT* ptr = &C[(size_t)(rbase + r) * ldc + col];
        if constexpr (sizeof(CT) == 4) *(float*)ptr = v;
        else                           *ptr = f2bf(v);
      }
    }
  }
}

// ---- Q = x Wq^T, K = x Wk^T: 256 blocks of 256x256 (exactly 1 round) ----
__global__ __launch_bounds__(512, 2) void proj_qk_kernel(
    const u16* __restrict__ xb, const u16* __restrict__ wqb,
    const u16* __restrict__ wkb, u16* __restrict__ Qb, u16* __restrict__ Kb) {
  __shared__ __align__(16) u16 lds[65536];
  const int bid = blockIdx.x;
  const int w = bid >> 7, r = bid & 127;
  const int rb = r >> 2, n0 = (r & 3) * 256;
  const u16* B = w ? wkb : wqb;
  u16* C = w ? Kb : Qb;
  gemm_core<u16, 256>(lds, xb + (size_t)rb * 256 * 1024, B + (size_t)n0 * 1024,
                      C, 16, 1024, 1024, 1024, rb * 256, n0);
}

// ---- qktvt: EXACTLY 256 equal-length coarse blocks (one clean round).
//   bid 0..143:  qkt 256x256 lower-tri tiles (36 per batch)
//   bid 144..255: vt coarse 256x256 for keys 0..1791 (7 key-blocks x 4d x 4z)
__global__ __launch_bounds__(512, 2) void qktvt_kernel(
    const u16* __restrict__ Qb, const u16* __restrict__ Kb, float* __restrict__ Sb,
    const u16* __restrict__ wvb, const u16* __restrict__ xb, u16* __restrict__ VTb) {
  __shared__ __align__(16) u16 lds[65536];
  const int bid = blockIdx.x;
  if (bid < 144) {
    const int z = bid / 36, xt = bid % 36;
    int m = 0;
    while ((m + 1) * (m + 2) / 2 <= xt) ++m;
    const int n = xt - m * (m + 1) / 2;
    gemm_core<float, 256>(lds,
        Qb + ((size_t)z * 2048 + m * 256) * 1024,
        Kb + ((size_t)z * 2048 + n * 256) * 1024,
        Sb + (size_t)z * 2048 * 2048,
        16, 1024, 1024, 2048, m * 256, n * 256);
  } else {
    const int j = bid - 144;                  // 0..111
    const int z = j / 28, r2 = j % 28, d = r2 / 7, kb = r2 % 7;
    gemm_core<u16, 256>(lds, wvb + (size_t)d * 256 * 1024,
                        xb + (size_t)z * 2048 * 1024 + (size_t)kb * 256 * 1024,
                        VTb + (size_t)z * 1024 * 2048,
                        16, 1024, 1024, 2048, d * 256, kb * 256);
  }
}

// ---- smvtk: 64 vtK-half chunks (keys 1792..2047, fp32 partials) + 512 sm ----
// vtK chunk: [256 dims x 128 keys] x K-half (nt=8), BN=128 core.
// Partials land in Sb's DEAD region: rows 0..511, fp32 cols 1024..2047 per z
// (qkt/sm never touch cols>=1024 for rows<1024; pv slot2 reuses only after vtfix).
__global__ __launch_bounds__(512, 2) void smvtk_kernel(
    float* __restrict__ Sb,
    const u16* __restrict__ wvb, const u16* __restrict__ xb) {
  __shared__ __align__(16) u16 lds[65536];
  const int bid = blockIdx.x;
  const int tid = threadIdx.x;
  if (bid < 64) {
    const int z = bid >> 4, r = bid & 15;
    const int d = r >> 2, kf = (r >> 1) & 1, h = r & 1;
    const u16* A = wvb + (size_t)d * 256 * 1024 + h * 512;
    const u16* B = xb + ((size_t)z * 2048 + 1792 + kf * 128) * 1024 + h * 512;
    const int i = (d * 2 + kf) * 2 + h;        // slot-partial 0..15
    const int band = i >> 3, coli = i & 7;
    float* C = Sb + (size_t)z * 2048 * 2048 + (size_t)band * 256 * 2048 +
               1024 + coli * 128;
    gemm_core<float, 128>(lds, A, B, C, 8, 1024, 1024, 2048, 0, 0);
    return;
  }
  // softmax: 16 rows per block; desc-m so long rows start first
  const int j = bid - 64;
  const int m = 7 - (j >> 6), z = (j >> 4) & 3, s = j & 15;
  const int iters = m + 1;
  const int wvid = tid >> 6, lane = tid & 63;
  float* S0 = Sb + (size_t)z * 2048 * 2048;
  for (int rr = wvid; rr < 16; rr += 8) {
    const int r = m * 256 + s * 16 + rr;
    float* row = S0 + (size_t)r * 2048;
    float vals[8][4];
    float mx = -3.4e38f;
#pragma unroll
    for (int it2 = 0; it2 < 8; ++it2)
      if (it2 < iters) {
        const int idx = it2 * 64 + lane;
        float4 v = ((const float4*)row)[idx];
        const int j0 = idx * 4;
        vals[it2][0] = (j0 <= r) ? v.x * 0.03125f : -3.4e38f;
        vals[it2][1] = (j0 + 1 <= r) ? v.y * 0.03125f : -3.4e38f;
        vals[it2][2] = (j0 + 2 <= r) ? v.z * 0.03125f : -3.4e38f;
        vals[it2][3] = (j0 + 3 <= r) ? v.w * 0.03125f : -3.4e38f;
        mx = fmaxf(mx, fmaxf(fmaxf(vals[it2][0], vals[it2][1]),
                             fmaxf(vals[it2][2], vals[it2][3])));
      }
#pragma unroll
    for (int o = 32; o; o >>= 1) mx = fmaxf(mx, __shfl_xor(mx, o, 64));
    float sum = 0.f;
#pragma unroll
    for (int it2 = 0; it2 < 8; ++it2)
      if (it2 < iters) {
#pragma unroll
        for (int e = 0; e < 4; ++e) {
          const float pp = __expf(vals[it2][e] - mx);
          vals[it2][e] = pp;
          sum += pp;
        }
      }
#pragma unroll
    for (int o = 32; o; o >>= 1) sum += __shfl_xor(sum, o, 64);
    const float rcp = 1.f / sum;
    u16* prow = (u16*)row;
#pragma unroll
    for (int it2 = 0; it2 < 8; ++it2)
      if (it2 < iters) {
        ushort4 o4;
        o4.x = f2bf(vals[it2][0] * rcp);
        o4.y = f2bf(vals[it2][1] * rcp);
        o4.z = f2bf(vals[it2][2] * rcp);
        o4.w = f2bf(vals[it2][3] * rcp);
        ((ushort4*)prow)[it2 * 64 + lane] = o4;
      }
  }
}

// ---- vtfix: VT[keys 1792..2047] = bf16(P0 + P1) from the K-half partials ----
__global__ __launch_bounds__(256) void vtfix_kernel(const float* __restrict__ Sb,
                                                    u16* __restrict__ VTb) {
  const int bid = blockIdx.x;            // 32 blocks: z(4) x sdk(8)
  const int z = bid >> 3, sdk = bid & 7;
  const int d = sdk >> 1, kf = sdk & 1;
  const int i0 = sdk * 2;
  const int band = i0 >> 3, coli = i0 & 7;
  const float* P0 = Sb + (size_t)z * 2048 * 2048 + (size_t)band * 256 * 2048 +
                    1024 + coli * 128;
  const float* P1 = P0 + 128;
  u16* dst = VTb + (size_t)z * 1024 * 2048 + (size_t)d * 256 * 2048 +
             1792 + kf * 128;
  for (int k = threadIdx.x; k < 8192; k += 256) {   // 256 rows x 32 float4
    const int r = k >> 5, c4 = (k & 31) << 2;
    float4 a = *(const float4*)(P0 + (size_t)r * 2048 + c4);
    float4 b = *(const float4*)(P1 + (size_t)r * 2048 + c4);
    ushort4 o;
    o.x = f2bf(a.x + b.x); o.y = f2bf(a.y + b.y);
    o.z = f2bf(a.z + b.z); o.w = f2bf(a.w + b.w);
    *(ushort4*)(dst + (size_t)r * 2048 + c4) = o;
  }
}

// pv chunk classes (desc nt): m-tile, k0 (K-tiles), nt, slot (0=out,1=slot1,2=slot2)
__constant__ signed char CPM[16] = {5,5,7,7,7,6,4,4,6,6,3,3,1,2,2,0};
__constant__ signed char CPK[16] = {0,12,0,11,22,0,0,10,10,19,0,8,0,0,6,0};
__constant__ signed char CPN[16] = {12,12,11,11,10,10,10,10,9,9,8,8,8,6,6,4};
__constant__ signed char CPS[16] = {0,1,0,1,2,0,0,1,1,2,0,1,0,0,1,0};

// ---- O_b = P_b VT_b^T (fp32); no atomics; slots carved from Sb's dead region ----
__global__ __launch_bounds__(512, 2) void pv_kernel(
    const u16* __restrict__ P, const u16* __restrict__ VTb,
    float* __restrict__ out, float* __restrict__ Sb) {
  __shared__ __align__(16) u16 lds[65536];
  const int cls = blockIdx.x, n = blockIdx.y;
  const size_t z = blockIdx.z;
  const int m = CPM[cls], k0 = CPK[cls], ntc = CPN[cls], sl = CPS[cls];
  const u16* Ap = P + z * 2048 * 4096 + (size_t)m * 256 * 4096 + (size_t)k0 * 64;
  const u16* Bp = VTb + z * 1024 * 2048 + (size_t)n * 256 * 2048 + (size_t)k0 * 64;
  float* Cp;
  int ldc;
  if (sl == 0) { Cp = out + z * 2048 * 1024; ldc = 1024; }
  else if (sl == 1) { Cp = Sb + z * 2048 * 2048 + 1024; ldc = 2048; }
  else { Cp = Sb + z * 2048 * 2048 + 1024 - (size_t)1536 * 2048; ldc = 2048; }
  gemm_core<float, 256>(lds, Ap, Bp, Cp, ntc, 4096, 2048, ldc, m * 256, n * 256);
}

// ---- out += slot1 (+slot2 for m>=6), fixed order -> deterministic ----
__global__ __launch_bounds__(256) void reduce_kernel(float* __restrict__ out,
                                                     const float* __restrict__ Sb) {
  const int j = blockIdx.x;
  const int m = 2 + (j >> 5), z = (j >> 3) & 3, s = j & 7;
  float* ob = out + (size_t)z * 2048 * 1024;
  const float* s1 = Sb + (size_t)z * 2048 * 2048 + 1024;
  const float* s2 = s1 - (size_t)1536 * 2048;
  const int r0 = m * 256 + s * 32;
  for (int k = threadIdx.x; k < 32 * 256; k += 256) {   // 32 rows x 256 float4
    const int rr = r0 + (k >> 8), cc = k & 255;
    float4 o = ((float4*)(ob + (size_t)rr * 1024))[cc];
    float4 a = ((const float4*)(s1 + (size_t)rr * 2048))[cc];
    o.x += a.x; o.y += a.y; o.z += a.z; o.w += a.w;
    if (m >= 6) {
      float4 b = ((const float4*)(s2 + (size_t)rr * 2048))[cc];
      o.x += b.x; o.y += b.y; o.z += b.z; o.w += b.w;
    }
    ((float4*)(ob + (size_t)rr * 1024))[cc] = o;
  }
}

extern "C" void kernel_launch(void* const* d_in, const int* in_sizes, int n_in,
                              void* d_out, int out_size, void* d_ws, size_t ws_size,
                              hipStream_t stream) {
  const float* x  = (const float*)d_in[0];
  const float* Wq = (const float*)d_in[1];
  const float* Wk = (const float*)d_in[2];
  const float* Wv = (const float*)d_in[3];
  float* out = (float*)d_out;

  char* ws = (char*)d_ws;
  u16* xb   = (u16*)(ws);                        // 16 MB  x bf16 [8192][1024]
  u16* wqb  = (u16*)(ws + (16ul << 20));         //  2 MB
  u16* wkb  = (u16*)(ws + (18ul << 20));         //  2 MB
  u16* wvb  = (u16*)(ws + (20ul << 20));         //  2 MB
  u16* Qb   = (u16*)(ws + (22ul << 20));         // 16 MB  Q bf16 [4][2048][1024]
  u16* Kb   = (u16*)(ws + (38ul << 20));         // 16 MB  K bf16
  u16* VTb  = (u16*)(ws + (54ul << 20));         // 16 MB  V^T bf16 [4][1024][2048]
  float* Sb = (float*)(ws + (70ul << 20));       // 64 MB  scores fp32; P bf16 in low
                                                 //        cols; dead region hosts vtK
                                                 //        partials then pv slot1/slot2

  cvt_all_kernel<<<11264, 256, 0, stream>>>(x, Wq, Wk, Wv, xb, wqb, wkb, wvb);

  proj_qk_kernel<<<256, 512, 0, stream>>>(xb, wqb, wkb, Qb, Kb);

  qktvt_kernel<<<256, 512, 0, stream>>>(Qb, Kb, Sb, wvb, xb, VTb);

  smvtk_kernel<<<576, 512, 0, stream>>>(Sb, wvb, xb);

  vtfix_kernel<<<32, 256, 0, stream>>>(Sb, VTb);

  pv_kernel<<<dim3(16, 4, 4), 512, 0, stream>>>((const u16*)Sb, VTb, out, Sb);

  reduce_kernel<<<192, 256, 0, stream>>>(out, Sb);
}

// Round 10
// 160.977 us; speedup vs baseline: 1.0726x; 1.0726x over previous
//
#include <hip/hip_runtime.h>

typedef unsigned short u16;
typedef unsigned int u32;
typedef __bf16 bf16x8 __attribute__((ext_vector_type(8)));
typedef float f32x4 __attribute__((ext_vector_type(4)));

#define AS1 __attribute__((address_space(1)))
#define AS3 __attribute__((address_space(3)))

// ---- fp32 -> bf16 (RNE) ----
__device__ inline u16 f2bf(float f) {
  union { float f; unsigned u; } a; a.f = f;
  unsigned u = a.u;
  return (u16)((u + 0x7fffu + ((u >> 16) & 1u)) >> 16);
}
__device__ inline float bf2f(u16 h) {
  union { unsigned u; float f; } a; a.u = ((u32)h) << 16; return a.f;
}

// ---- all fp32 -> bf16 converts in one dispatch ----
__global__ __launch_bounds__(256) void cvt_all_kernel(
    const float* __restrict__ x, const float* __restrict__ wq,
    const float* __restrict__ wk, const float* __restrict__ wv,
    u16* __restrict__ xb, u16* __restrict__ wqb,
    u16* __restrict__ wkb, u16* __restrict__ wvb) {
  int bid = blockIdx.x;
  const float* in; u16* out;
  if (bid < 8192) { in = x; out = xb; }
  else if (bid < 9216) { in = wq; out = wqb; bid -= 8192; }
  else if (bid < 10240) { in = wk; out = wkb; bid -= 9216; }
  else { in = wv; out = wvb; bid -= 10240; }
  size_t i = ((size_t)bid * 256 + threadIdx.x) * 4;
  float4 v = *(const float4*)(in + i);
  ushort4 o;
  o.x = f2bf(v.x); o.y = f2bf(v.y); o.z = f2bf(v.z); o.w = f2bf(v.w);
  *(ushort4*)(out + i) = o;
}

// ============================================================================
// 256xBN 8-wave GEMM core, 4-phase dead-region schedule: C = A @ B^T.
//   BN=256: wave tile 128x64, 16 MFMA/phase; BN=128: wave tile 128x32, 8/phase.
//   RAW s_barrier only; counted vmcnt (never drains the prefetch queue).
//   T2 swizzle: 16B slot ^= (row&7) on both staged source and ds_read.
//   (correctness + ~905 TF/block @K=1024 proven rounds 3-9)
// ============================================================================
template <typename CT, int BN>
__device__ __forceinline__ void gemm_core(
    u16* __restrict__ lds,
    const u16* __restrict__ A, const u16* __restrict__ B, CT* __restrict__ C,
    int nt, int lda, int ldb, int ldc, int m0, int n0) {
  constexpr int ABUF = 16384;      // 256 rows x 64 u16 per A buffer
  constexpr int BBUF = BN * 64;
  constexpr int BSW = BN / 64;     // B staging sweeps per tile (4 or 2)
  constexpr int NI = BN / 64;      // n-frags per wave

  const int tid = threadIdx.x;
  const int ln = tid & 63, wv = tid >> 6;
  const int wr = wv >> 2, wc = wv & 3;  // 2 x 4 wave grid

  auto sweep = [&](const u16* src, int ld, int t, int s, int base) {
    const int c = s * 512 + tid;
    const int row = c >> 3, slot = c & 7;
    const int col = (slot ^ (row & 7)) * 8;
    __builtin_amdgcn_global_load_lds(
        (const AS1 void*)(src + (size_t)row * ld + (size_t)t * 64 + col),
        (AS3 void*)(&lds[base + c * 8]), 16, 0, 0);
  };

  f32x4 acc[8][NI] = {};

  // prologue: tiles 0 and 1 fully staged
#pragma unroll
  for (int s = 0; s < BSW; ++s) sweep(B, ldb, 0, s, 2 * ABUF);
#pragma unroll
  for (int s = 0; s < 4; ++s) sweep(A, lda, 0, s, 0);
  if (nt > 1) {
#pragma unroll
    for (int s = 0; s < BSW; ++s) sweep(B, ldb, 1, s, 2 * ABUF + BBUF);
#pragma unroll
    for (int s = 0; s < 4; ++s) sweep(A, lda, 1, s, ABUF);
    if constexpr (BSW == 4) asm volatile("s_waitcnt vmcnt(8)" ::: "memory");
    else                    asm volatile("s_waitcnt vmcnt(6)" ::: "memory");
  } else {
    asm volatile("s_waitcnt vmcnt(0)" ::: "memory");
  }
  __builtin_amdgcn_s_barrier();

  for (int t = 0; t < nt; ++t) {
    const int p = t & 1;
    const u16* La = &lds[p * ABUF];
    const u16* Lb = &lds[2 * ABUF + p * BBUF];
    bf16x8 bfr[NI][2];
#pragma unroll
    for (int q = 0; q < 4; ++q) {
      if (q == 0) {
        __builtin_amdgcn_sched_barrier(0);  // pin reads below publishing barrier
#pragma unroll
        for (int ni = 0; ni < NI; ++ni)
#pragma unroll
          for (int ks = 0; ks < 2; ++ks) {
            const int row = wc * (BN / 4) + ni * 16 + (ln & 15);
            const int kc = ks * 4 + (ln >> 4);
            bfr[ni][ks] = *(const bf16x8*)&Lb[row * 64 + ((kc ^ (row & 7)) << 3)];
          }
      }
      bf16x8 afr[2][2];
#pragma unroll
      for (int mi = 0; mi < 2; ++mi)
#pragma unroll
        for (int ks = 0; ks < 2; ++ks) {
          const int row = wr * 128 + (q * 2 + mi) * 16 + (ln & 15);
          const int kc = ks * 4 + (ln >> 4);
          afr[mi][ks] = *(const bf16x8*)&La[row * 64 + ((kc ^ (row & 7)) << 3)];
        }
      // dead-region staging
      if (q == 0)      { if (t >= 1 && t + 1 < nt) { sweep(A, lda, t + 1, 0, (p ^ 1) * ABUF); sweep(A, lda, t + 1, 1, (p ^ 1) * ABUF); } }
      else if (q == 1) { if (t >= 1 && t + 1 < nt) { sweep(A, lda, t + 1, 2, (p ^ 1) * ABUF); sweep(A, lda, t + 1, 3, (p ^ 1) * ABUF); } }
      else if (q == 2) { if (t + 2 < nt) { sweep(B, ldb, t + 2, 0, 2 * ABUF + p * BBUF); if (BSW == 4) sweep(B, ldb, t + 2, 1, 2 * ABUF + p * BBUF); } }
      else             { if (t + 2 < nt) { if (BSW == 4) { sweep(B, ldb, t + 2, 2, 2 * ABUF + p * BBUF); sweep(B, ldb, t + 2, 3, 2 * ABUF + p * BBUF); } else { sweep(B, ldb, t + 2, 1, 2 * ABUF + p * BBUF); } } }

      __builtin_amdgcn_s_barrier();
      __builtin_amdgcn_s_setprio(1);
#pragma unroll
      for (int mi = 0; mi < 2; ++mi)
#pragma unroll
        for (int ni = 0; ni < NI; ++ni)
#pragma unroll
          for (int ks = 0; ks < 2; ++ks)
            acc[q * 2 + mi][ni] = __builtin_amdgcn_mfma_f32_16x16x32_bf16(
                afr[mi][ks], bfr[ni][ks], acc[q * 2 + mi][ni], 0, 0, 0);
      __builtin_amdgcn_s_setprio(0);
      if (q == 3) {
        if (t + 2 < nt) {
          if constexpr (BSW == 4) asm volatile("s_waitcnt vmcnt(4)" ::: "memory");
          else                    asm volatile("s_waitcnt vmcnt(2)" ::: "memory");
        } else if (t + 1 < nt) {
          asm volatile("s_waitcnt vmcnt(0)" ::: "memory");
        }
      }
      __builtin_amdgcn_s_barrier();
    }
  }

  // epilogue: D col = lane&15 (n), row = (lane>>4)*4 + reg (m)
#pragma unroll
  for (int mi = 0; mi < 8; ++mi) {
    const int rbase = m0 + wr * 128 + mi * 16 + (ln >> 4) * 4;
#pragma unroll
    for (int ni = 0; ni < NI; ++ni) {
      const int col = n0 + wc * (BN / 4) + ni * 16 + (ln & 15);
#pragma unroll
      for (int r = 0; r < 4; ++r) {
        const float v = acc[mi][ni][r];
        CT* ptr = &C[(size_t)(rbase + r) * ldc + col];
        if constexpr (sizeof(CT) == 4) *(float*)ptr = v;
        else                           *ptr = f2bf(v);
      }
    }
  }
}

// ---- Q = x Wq^T, K = x Wk^T: 256 blocks of 256x256 (exactly 1 round) ----
__global__ __launch_bounds__(512, 2) void proj_qk_kernel(
    const u16* __restrict__ xb, const u16* __restrict__ wqb,
    const u16* __restrict__ wkb, u16* __restrict__ Qb, u16* __restrict__ Kb) {
  __shared__ __align__(16) u16 lds[65536];
  const int bid = blockIdx.x;
  const int w = bid >> 7, r = bid & 127;
  const int rb = r >> 2, n0 = (r & 3) * 256;
  const u16* B = w ? wkb : wqb;
  u16* C = w ? Kb : Qb;
  gemm_core<u16, 256>(lds, xb + (size_t)rb * 256 * 1024, B + (size_t)n0 * 1024,
                      C, 16, 1024, 1024, 1024, rb * 256, n0);
}

// ---- qktvt: 256 coarse blocks, XCD-locality swizzled.
//   item = (bid&7)*32 + (bid>>3): each XCD (bid%8) gets 32 CONSECUTIVE items.
//   items 0..143: qkt (z-major triangular -> shared Q/K row-blocks per XCD),
//                 S written BF16 into Sb16.
//   items 144..255: vt coarse 256x256 keys 0..1791 (z,d,kb order). ----
__global__ __launch_bounds__(512, 2) void qktvt_kernel(
    const u16* __restrict__ Qb, const u16* __restrict__ Kb, u16* __restrict__ Sb16,
    const u16* __restrict__ wvb, const u16* __restrict__ xb, u16* __restrict__ VTb) {
  __shared__ __align__(16) u16 lds[65536];
  const int bid = blockIdx.x;
  const int item = (bid & 7) * 32 + (bid >> 3);   // bijective 0..255
  if (item < 144) {
    const int z = item / 36, xt = item % 36;
    int m = 0;
    while ((m + 1) * (m + 2) / 2 <= xt) ++m;
    const int n = xt - m * (m + 1) / 2;
    gemm_core<u16, 256>(lds,
        Qb + ((size_t)z * 2048 + m * 256) * 1024,
        Kb + ((size_t)z * 2048 + n * 256) * 1024,
        Sb16 + (size_t)z * 2048 * 2048,
        16, 1024, 1024, 2048, m * 256, n * 256);
  } else {
    const int j = item - 144;                 // 0..111
    const int z = j / 28, r2 = j % 28, d = r2 / 7, kb = r2 % 7;
    gemm_core<u16, 256>(lds, wvb + (size_t)d * 256 * 1024,
                        xb + (size_t)z * 2048 * 1024 + (size_t)kb * 256 * 1024,
                        VTb + (size_t)z * 1024 * 2048,
                        16, 1024, 1024, 2048, d * 256, kb * 256);
  }
}

// ---- smvt: 32 vtK chunks (BN=256, nt=8, fp32 partials) + 512 softmax blocks.
// vtK: VT keys 1792..2047, K split in halves; partial (z,d,h) [256d x 256k] f32
//      lives in the slot2 area R[z]+1572864+(d*2+h)*65536 (dead until vtfix).
// sm: bf16 S rows -> bf16 P in place (16 rows/block, desc-m). ----
__global__ __launch_bounds__(512, 2) void smvt_kernel(
    u16* __restrict__ Sb16, float* __restrict__ R,
    const u16* __restrict__ wvb, const u16* __restrict__ xb) {
  __shared__ __align__(16) u16 lds[65536];
  const int bid = blockIdx.x;
  const int tid = threadIdx.x;
  if (bid < 32) {
    const int z = bid >> 3, r = bid & 7;
    const int d = r >> 1, h = r & 1;
    const u16* A = wvb + (size_t)d * 256 * 1024 + h * 512;
    const u16* B = xb + ((size_t)z * 2048 + 1792) * 1024 + h * 512;
    float* C = R + (size_t)z * 2097152 + 1572864 + (d * 2 + h) * 65536;
    gemm_core<float, 256>(lds, A, B, C, 8, 1024, 1024, 256, 0, 0);
    return;
  }
  // softmax on bf16 S: 16 rows per block
  const int j = bid - 32;
  const int m = 7 - (j >> 6), z = (j >> 4) & 3, s = j & 15;
  const int iters = (m + 2) >> 1;            // ceil((m+1)*256 / 512)
  const int wvid = tid >> 6, lane = tid & 63;
  u16* S0 = Sb16 + (size_t)z * 2048 * 2048;
  for (int rr = wvid; rr < 16; rr += 8) {
    const int r = m * 256 + s * 16 + rr;
    u16* row = S0 + (size_t)r * 2048;
    float vals[4][8];
    float mx = -3.4e38f;
#pragma unroll
    for (int it2 = 0; it2 < 4; ++it2)
      if (it2 < iters) {
        const int idx8 = it2 * 512 + lane * 8;
        uint4 w = *(const uint4*)(row + idx8);
        const u32 ws[4] = {w.x, w.y, w.z, w.w};
#pragma unroll
        for (int e = 0; e < 8; ++e) {
          const u16 hb = (u16)(ws[e >> 1] >> ((e & 1) * 16));
          const float xv = bf2f(hb) * 0.03125f;
          vals[it2][e] = (idx8 + e <= r) ? xv : -3.4e38f;
          mx = fmaxf(mx, vals[it2][e]);
        }
      }
#pragma unroll
    for (int o = 32; o; o >>= 1) mx = fmaxf(mx, __shfl_xor(mx, o, 64));
    float sum = 0.f;
#pragma unroll
    for (int it2 = 0; it2 < 4; ++it2)
      if (it2 < iters) {
#pragma unroll
        for (int e = 0; e < 8; ++e) {
          const float pp = __expf(vals[it2][e] - mx);
          vals[it2][e] = pp;
          sum += pp;
        }
      }
#pragma unroll
    for (int o = 32; o; o >>= 1) sum += __shfl_xor(sum, o, 64);
    const float rcp = 1.f / sum;
#pragma unroll
    for (int it2 = 0; it2 < 4; ++it2)
      if (it2 < iters) {
        const int idx8 = it2 * 512 + lane * 8;
        uint4 w;
        u32 wo[4];
#pragma unroll
        for (int e2 = 0; e2 < 4; ++e2) {
          const u16 lo = f2bf(vals[it2][e2 * 2] * rcp);
          const u16 hi = f2bf(vals[it2][e2 * 2 + 1] * rcp);
          wo[e2] = (u32)lo | ((u32)hi << 16);
        }
        w.x = wo[0]; w.y = wo[1]; w.z = wo[2]; w.w = wo[3];
        *(uint4*)(row + idx8) = w;
      }
  }
}

// ---- vtfix: VT[z][dims][keys 1792..2047] = bf16(P(d,0) + P(d,1)) ----
__global__ __launch_bounds__(256) void vtfix_kernel(const float* __restrict__ R,
                                                    u16* __restrict__ VTb) {
  const int bid = blockIdx.x;            // 32: z(4) x d(4) x rowhalf(2)
  const int z = bid >> 3, q = bid & 7;
  const int d = q >> 1, rh = q & 1;
  const float* P0 = R + (size_t)z * 2097152 + 1572864 + (d * 2 + 0) * 65536;
  const float* P1 = R + (size_t)z * 2097152 + 1572864 + (d * 2 + 1) * 65536;
  for (int k = threadIdx.x; k < 128 * 64; k += 256) {   // 128 dims x 64 float4
    const int dp = rh * 128 + (k >> 6), c4 = (k & 63) * 4;
    float4 a = *(const float4*)(P0 + (size_t)dp * 256 + c4);
    float4 b = *(const float4*)(P1 + (size_t)dp * 256 + c4);
    ushort4 o;
    o.x = f2bf(a.x + b.x); o.y = f2bf(a.y + b.y);
    o.z = f2bf(a.z + b.z); o.w = f2bf(a.w + b.w);
    *(ushort4*)(VTb + (size_t)z * 1024 * 2048 + (size_t)(d * 256 + dp) * 2048 +
                1792 + c4) = o;
  }
}

// pv chunk classes (desc nt): m-tile, k0 (K-tiles), nt, slot (0=out,1=slot1,2=slot2)
__constant__ signed char CPM[16] = {5,5,7,7,7,6,4,4,6,6,3,3,1,2,2,0};
__constant__ signed char CPK[16] = {0,12,0,11,22,0,0,10,10,19,0,8,0,0,6,0};
__constant__ signed char CPN[16] = {12,12,11,11,10,10,10,10,9,9,8,8,8,6,6,4};
__constant__ signed char CPS[16] = {0,1,0,1,2,0,0,1,1,2,0,1,0,0,1,0};

// ---- O_b = P_b VT_b^T (fp32); no atomics; slots in dedicated R buffers ----
__global__ __launch_bounds__(512, 2) void pv_kernel(
    const u16* __restrict__ P, const u16* __restrict__ VTb,
    float* __restrict__ out, float* __restrict__ R) {
  __shared__ __align__(16) u16 lds[65536];
  const int cls = blockIdx.x, n = blockIdx.y;
  const size_t z = blockIdx.z;
  const int m = CPM[cls], k0 = CPK[cls], ntc = CPN[cls], sl = CPS[cls];
  const u16* Ap = P + z * 2048 * 2048 + (size_t)m * 256 * 2048 + (size_t)k0 * 64;
  const u16* Bp = VTb + z * 1024 * 2048 + (size_t)n * 256 * 2048 + (size_t)k0 * 64;
  float* Cp;
  // slot1 holds out-rows 512..2047 (base shifted by -512 rows);
  // slot2 holds out-rows 1536..2047 (base = R_z exactly).
  if (sl == 0)      Cp = out + z * 2048 * 1024;
  else if (sl == 1) Cp = R + z * 2097152 - (size_t)512 * 1024;
  else              Cp = R + z * 2097152;
  gemm_core<float, 256>(lds, Ap, Bp, Cp, ntc, 2048, 2048, 1024, m * 256, n * 256);
}

// ---- out += slot1 (+slot2 for m>=6), fixed order -> deterministic ----
__global__ __launch_bounds__(256) void reduce_kernel(float* __restrict__ out,
                                                     const float* __restrict__ R) {
  const int j = blockIdx.x;
  const int m = 2 + (j >> 5), z = (j >> 3) & 3, s = j & 7;
  float* ob = out + (size_t)z * 2048 * 1024;
  const float* s1 = R + (size_t)z * 2097152;
  const float* s2 = s1 + 1572864;
  const int r0 = m * 256 + s * 32;
  for (int k = threadIdx.x; k < 32 * 256; k += 256) {   // 32 rows x 256 float4
    const int rr = r0 + (k >> 8), cc = k & 255;
    float4 o = ((float4*)(ob + (size_t)rr * 1024))[cc];
    float4 a = ((const float4*)(s1 + (size_t)(rr - 512) * 1024))[cc];
    o.x += a.x; o.y += a.y; o.z += a.z; o.w += a.w;
    if (m >= 6) {
      float4 b = ((const float4*)(s2 + (size_t)(rr - 1536) * 1024))[cc];
      o.x += b.x; o.y += b.y; o.z += b.z; o.w += b.w;
    }
    ((float4*)(ob + (size_t)rr * 1024))[cc] = o;
  }
}

extern "C" void kernel_launch(void* const* d_in, const int* in_sizes, int n_in,
                              void* d_out, int out_size, void* d_ws, size_t ws_size,
                              hipStream_t stream) {
  const float* x  = (const float*)d_in[0];
  const float* Wq = (const float*)d_in[1];
  const float* Wk = (const float*)d_in[2];
  const float* Wv = (const float*)d_in[3];
  float* out = (float*)d_out;

  char* ws = (char*)d_ws;
  u16* xb   = (u16*)(ws);                        // 16 MB  x bf16 [8192][1024]
  u16* wqb  = (u16*)(ws + (16ul << 20));         //  2 MB
  u16* wkb  = (u16*)(ws + (18ul << 20));         //  2 MB
  u16* wvb  = (u16*)(ws + (20ul << 20));         //  2 MB
  u16* Qb   = (u16*)(ws + (22ul << 20));         // 16 MB  Q bf16 [4][2048][1024]
  u16* Kb   = (u16*)(ws + (38ul << 20));         // 16 MB  K bf16
  u16* VTb  = (u16*)(ws + (54ul << 20));         // 16 MB  V^T bf16 [4][1024][2048]
  u16* Sb16 = (u16*)(ws + (70ul << 20));         // 32 MB  S/P bf16 [4][2048][2048]
  float* R  = (float*)(ws + (102ul << 20));      // 32 MB  per z: slot1 (1536x1024)
                                                 //        + slot2/vtK (512x1024)

  cvt_all_kernel<<<11264, 256, 0, stream>>>(x, Wq, Wk, Wv, xb, wqb, wkb, wvb);

  proj_qk_kernel<<<256, 512, 0, stream>>>(xb, wqb, wkb, Qb, Kb);

  qktvt_kernel<<<256, 512, 0, stream>>>(Qb, Kb, Sb16, wvb, xb, VTb);

  smvt_kernel<<<544, 512, 0, stream>>>(Sb16, R, wvb, xb);

  vtfix_kernel<<<32, 256, 0, stream>>>(R, VTb);

  pv_kernel<<<dim3(16, 4, 4), 512, 0, stream>>>(Sb16, VTb, out, R);

  reduce_kernel<<<192, 256, 0, stream>>>(out, R);
}

// Round 11
// 160.960 us; speedup vs baseline: 1.0727x; 1.0001x over previous
//
#include <hip/hip_runtime.h>

typedef unsigned short u16;
typedef unsigned int u32;
typedef __bf16 bf16x8 __attribute__((ext_vector_type(8)));
typedef float f32x4 __attribute__((ext_vector_type(4)));

#define AS1 __attribute__((address_space(1)))
#define AS3 __attribute__((address_space(3)))

// ---- fp32 <-> bf16 ----
__device__ inline u16 f2bf(float f) {
  union { float f; unsigned u; } a; a.f = f;
  unsigned u = a.u;
  return (u16)((u + 0x7fffu + ((u >> 16) & 1u)) >> 16);
}
__device__ inline float bf2f(u16 h) {
  union { unsigned u; float f; } a; a.u = ((u32)h) << 16; return a.f;
}

// ---- all fp32 -> bf16 converts in one dispatch ----
__global__ __launch_bounds__(256) void cvt_all_kernel(
    const float* __restrict__ x, const float* __restrict__ wq,
    const float* __restrict__ wk, const float* __restrict__ wv,
    u16* __restrict__ xb, u16* __restrict__ wqb,
    u16* __restrict__ wkb, u16* __restrict__ wvb) {
  int bid = blockIdx.x;
  const float* in; u16* out;
  if (bid < 8192) { in = x; out = xb; }
  else if (bid < 9216) { in = wq; out = wqb; bid -= 8192; }
  else if (bid < 10240) { in = wk; out = wkb; bid -= 9216; }
  else { in = wv; out = wvb; bid -= 10240; }
  size_t i = ((size_t)bid * 256 + threadIdx.x) * 4;
  float4 v = *(const float4*)(in + i);
  ushort4 o;
  o.x = f2bf(v.x); o.y = f2bf(v.y); o.z = f2bf(v.z); o.w = f2bf(v.w);
  *(ushort4*)(out + i) = o;
}

// ============================================================================
// 256xBN 8-wave GEMM core, 4-phase dead-region schedule: C = A @ B^T.
//   BN=256: wave tile 128x64, 16 MFMA/phase; BN=128: wave tile 128x32, 8/phase.
//   RAW s_barrier only; counted vmcnt (never drains the prefetch queue).
//   T2 swizzle: 16B slot ^= (row&7) on both staged source and ds_read.
//   (correctness + ~905 TF/block @K=1024 proven rounds 3-10)
// ============================================================================
template <typename CT, int BN>
__device__ __forceinline__ void gemm_core(
    u16* __restrict__ lds,
    const u16* __restrict__ A, const u16* __restrict__ B, CT* __restrict__ C,
    int nt, int lda, int ldb, int ldc, int m0, int n0) {
  constexpr int ABUF = 16384;      // 256 rows x 64 u16 per A buffer
  constexpr int BBUF = BN * 64;
  constexpr int BSW = BN / 64;     // B staging sweeps per tile (4 or 2)
  constexpr int NI = BN / 64;      // n-frags per wave

  const int tid = threadIdx.x;
  const int ln = tid & 63, wv = tid >> 6;
  const int wr = wv >> 2, wc = wv & 3;  // 2 x 4 wave grid

  auto sweep = [&](const u16* src, int ld, int t, int s, int base) {
    const int c = s * 512 + tid;
    const int row = c >> 3, slot = c & 7;
    const int col = (slot ^ (row & 7)) * 8;
    __builtin_amdgcn_global_load_lds(
        (const AS1 void*)(src + (size_t)row * ld + (size_t)t * 64 + col),
        (AS3 void*)(&lds[base + c * 8]), 16, 0, 0);
  };

  f32x4 acc[8][NI] = {};

  // prologue: tiles 0 and 1 fully staged
#pragma unroll
  for (int s = 0; s < BSW; ++s) sweep(B, ldb, 0, s, 2 * ABUF);
#pragma unroll
  for (int s = 0; s < 4; ++s) sweep(A, lda, 0, s, 0);
  if (nt > 1) {
#pragma unroll
    for (int s = 0; s < BSW; ++s) sweep(B, ldb, 1, s, 2 * ABUF + BBUF);
#pragma unroll
    for (int s = 0; s < 4; ++s) sweep(A, lda, 1, s, ABUF);
    if constexpr (BSW == 4) asm volatile("s_waitcnt vmcnt(8)" ::: "memory");
    else                    asm volatile("s_waitcnt vmcnt(6)" ::: "memory");
  } else {
    asm volatile("s_waitcnt vmcnt(0)" ::: "memory");
  }
  __builtin_amdgcn_s_barrier();

  for (int t = 0; t < nt; ++t) {
    const int p = t & 1;
    const u16* La = &lds[p * ABUF];
    const u16* Lb = &lds[2 * ABUF + p * BBUF];
    bf16x8 bfr[NI][2];
#pragma unroll
    for (int q = 0; q < 4; ++q) {
      if (q == 0) {
        __builtin_amdgcn_sched_barrier(0);  // pin reads below publishing barrier
#pragma unroll
        for (int ni = 0; ni < NI; ++ni)
#pragma unroll
          for (int ks = 0; ks < 2; ++ks) {
            const int row = wc * (BN / 4) + ni * 16 + (ln & 15);
            const int kc = ks * 4 + (ln >> 4);
            bfr[ni][ks] = *(const bf16x8*)&Lb[row * 64 + ((kc ^ (row & 7)) << 3)];
          }
      }
      bf16x8 afr[2][2];
#pragma unroll
      for (int mi = 0; mi < 2; ++mi)
#pragma unroll
        for (int ks = 0; ks < 2; ++ks) {
          const int row = wr * 128 + (q * 2 + mi) * 16 + (ln & 15);
          const int kc = ks * 4 + (ln >> 4);
          afr[mi][ks] = *(const bf16x8*)&La[row * 64 + ((kc ^ (row & 7)) << 3)];
        }
      // dead-region staging
      if (q == 0)      { if (t >= 1 && t + 1 < nt) { sweep(A, lda, t + 1, 0, (p ^ 1) * ABUF); sweep(A, lda, t + 1, 1, (p ^ 1) * ABUF); } }
      else if (q == 1) { if (t >= 1 && t + 1 < nt) { sweep(A, lda, t + 1, 2, (p ^ 1) * ABUF); sweep(A, lda, t + 1, 3, (p ^ 1) * ABUF); } }
      else if (q == 2) { if (t + 2 < nt) { sweep(B, ldb, t + 2, 0, 2 * ABUF + p * BBUF); if (BSW == 4) sweep(B, ldb, t + 2, 1, 2 * ABUF + p * BBUF); } }
      else             { if (t + 2 < nt) { if (BSW == 4) { sweep(B, ldb, t + 2, 2, 2 * ABUF + p * BBUF); sweep(B, ldb, t + 2, 3, 2 * ABUF + p * BBUF); } else { sweep(B, ldb, t + 2, 1, 2 * ABUF + p * BBUF); } } }

      __builtin_amdgcn_s_barrier();
      __builtin_amdgcn_s_setprio(1);
#pragma unroll
      for (int mi = 0; mi < 2; ++mi)
#pragma unroll
        for (int ni = 0; ni < NI; ++ni)
#pragma unroll
          for (int ks = 0; ks < 2; ++ks)
            acc[q * 2 + mi][ni] = __builtin_amdgcn_mfma_f32_16x16x32_bf16(
                afr[mi][ks], bfr[ni][ks], acc[q * 2 + mi][ni], 0, 0, 0);
      __builtin_amdgcn_s_setprio(0);
      if (q == 3) {
        if (t + 2 < nt) {
          if constexpr (BSW == 4) asm volatile("s_waitcnt vmcnt(4)" ::: "memory");
          else                    asm volatile("s_waitcnt vmcnt(2)" ::: "memory");
        } else if (t + 1 < nt) {
          asm volatile("s_waitcnt vmcnt(0)" ::: "memory");
        }
      }
      __builtin_amdgcn_s_barrier();
    }
  }

  // epilogue: D col = lane&15 (n), row = (lane>>4)*4 + reg (m)
#pragma unroll
  for (int mi = 0; mi < 8; ++mi) {
    const int rbase = m0 + wr * 128 + mi * 16 + (ln >> 4) * 4;
#pragma unroll
    for (int ni = 0; ni < NI; ++ni) {
      const int col = n0 + wc * (BN / 4) + ni * 16 + (ln & 15);
#pragma unroll
      for (int r = 0; r < 4; ++r) {
        const float v = acc[mi][ni][r];
        CT* ptr = &C[(size_t)(rbase + r) * ldc + col];
        if constexpr (sizeof(CT) == 4) *(float*)ptr = v;
        else                           *ptr = f2bf(v);
      }
    }
  }
}

// ---- Q = x Wq^T, K = x Wk^T: 256 blocks of 256x256 (exactly 1 round) ----
__global__ __launch_bounds__(512, 2) void proj_qk_kernel(
    const u16* __restrict__ xb, const u16* __restrict__ wqb,
    const u16* __restrict__ wkb, u16* __restrict__ Qb, u16* __restrict__ Kb) {
  __shared__ __align__(16) u16 lds[65536];
  const int bid = blockIdx.x;
  const int w = bid >> 7, r = bid & 127;
  const int rb = r >> 2, n0 = (r & 3) * 256;
  const u16* B = w ? wkb : wqb;
  u16* C = w ? Kb : Qb;
  gemm_core<u16, 256>(lds, xb + (size_t)rb * 256 * 1024, B + (size_t)n0 * 1024,
                      C, 16, 1024, 1024, 1024, rb * 256, n0);
}

// ---- qktvt: 256 coarse blocks, XCD-locality swizzled (round-10 proven).
//   items 0..143: qkt (S bf16), items 144..255: vt coarse keys 0..1791 ----
__global__ __launch_bounds__(512, 2) void qktvt_kernel(
    const u16* __restrict__ Qb, const u16* __restrict__ Kb, u16* __restrict__ Sb16,
    const u16* __restrict__ wvb, const u16* __restrict__ xb, u16* __restrict__ VTb) {
  __shared__ __align__(16) u16 lds[65536];
  const int bid = blockIdx.x;
  const int item = (bid & 7) * 32 + (bid >> 3);   // bijective 0..255
  if (item < 144) {
    const int z = item / 36, xt = item % 36;
    int m = 0;
    while ((m + 1) * (m + 2) / 2 <= xt) ++m;
    const int n = xt - m * (m + 1) / 2;
    gemm_core<u16, 256>(lds,
        Qb + ((size_t)z * 2048 + m * 256) * 1024,
        Kb + ((size_t)z * 2048 + n * 256) * 1024,
        Sb16 + (size_t)z * 2048 * 2048,
        16, 1024, 1024, 2048, m * 256, n * 256);
  } else {
    const int j = item - 144;                 // 0..111
    const int z = j / 28, r2 = j % 28, d = r2 / 7, kb = r2 % 7;
    gemm_core<u16, 256>(lds, wvb + (size_t)d * 256 * 1024,
                        xb + (size_t)z * 2048 * 1024 + (size_t)kb * 256 * 1024,
                        VTb + (size_t)z * 1024 * 2048,
                        16, 1024, 1024, 2048, d * 256, kb * 256);
  }
}

// ---- smvt: 64 vtK chunks (BN=256, nt=4, K-quarters) + 512 softmax blocks.
// vtK: VT keys 1792..2047; partial (z,d,h) [256d x 256k] f32 at
//      R_z + (d*4+h)*65536 (front of R_z; dead until vtfix, overwritten by
//      pv slots only in the LATER pv dispatch). ----
__global__ __launch_bounds__(512, 2) void smvt_kernel(
    u16* __restrict__ Sb16, float* __restrict__ R,
    const u16* __restrict__ wvb, const u16* __restrict__ xb) {
  __shared__ __align__(16) u16 lds[65536];
  const int bid = blockIdx.x;
  const int tid = threadIdx.x;
  if (bid < 64) {
    const int z = bid >> 4, r = bid & 15;
    const int d = r >> 2, h = r & 3;
    const u16* A = wvb + (size_t)d * 256 * 1024 + h * 256;
    const u16* B = xb + ((size_t)z * 2048 + 1792) * 1024 + h * 256;
    float* C = R + (size_t)z * 2097152 + (d * 4 + h) * 65536;
    gemm_core<float, 256>(lds, A, B, C, 4, 1024, 1024, 256, 0, 0);
    return;
  }
  // softmax on bf16 S: 16 rows per block, desc-m
  const int j = bid - 64;
  const int m = 7 - (j >> 6), z = (j >> 4) & 3, s = j & 15;
  const int iters = (m + 2) >> 1;            // ceil((m+1)*256 / 512)
  const int wvid = tid >> 6, lane = tid & 63;
  u16* S0 = Sb16 + (size_t)z * 2048 * 2048;
  for (int rr = wvid; rr < 16; rr += 8) {
    const int r = m * 256 + s * 16 + rr;
    u16* row = S0 + (size_t)r * 2048;
    float vals[4][8];
    float mx = -3.4e38f;
#pragma unroll
    for (int it2 = 0; it2 < 4; ++it2)
      if (it2 < iters) {
        const int idx8 = it2 * 512 + lane * 8;
        uint4 w = *(const uint4*)(row + idx8);
        const u32 ws[4] = {w.x, w.y, w.z, w.w};
#pragma unroll
        for (int e = 0; e < 8; ++e) {
          const u16 hb = (u16)(ws[e >> 1] >> ((e & 1) * 16));
          const float xv = bf2f(hb) * 0.03125f;
          vals[it2][e] = (idx8 + e <= r) ? xv : -3.4e38f;
          mx = fmaxf(mx, vals[it2][e]);
        }
      }
#pragma unroll
    for (int o = 32; o; o >>= 1) mx = fmaxf(mx, __shfl_xor(mx, o, 64));
    float sum = 0.f;
#pragma unroll
    for (int it2 = 0; it2 < 4; ++it2)
      if (it2 < iters) {
#pragma unroll
        for (int e = 0; e < 8; ++e) {
          const float pp = __expf(vals[it2][e] - mx);
          vals[it2][e] = pp;
          sum += pp;
        }
      }
#pragma unroll
    for (int o = 32; o; o >>= 1) sum += __shfl_xor(sum, o, 64);
    const float rcp = 1.f / sum;
#pragma unroll
    for (int it2 = 0; it2 < 4; ++it2)
      if (it2 < iters) {
        const int idx8 = it2 * 512 + lane * 8;
        uint4 w;
        u32 wo[4];
#pragma unroll
        for (int e2 = 0; e2 < 4; ++e2) {
          const u16 lo = f2bf(vals[it2][e2 * 2] * rcp);
          const u16 hi = f2bf(vals[it2][e2 * 2 + 1] * rcp);
          wo[e2] = (u32)lo | ((u32)hi << 16);
        }
        w.x = wo[0]; w.y = wo[1]; w.z = wo[2]; w.w = wo[3];
        *(uint4*)(row + idx8) = w;
      }
  }
}

// ---- vtfix: VT[z][dims][keys 1792..2047] = bf16(sum of 4 K-quarter partials) ----
__global__ __launch_bounds__(256) void vtfix_kernel(const float* __restrict__ R,
                                                    u16* __restrict__ VTb) {
  const int bid = blockIdx.x;            // 32: z(4) x d(4) x rowhalf(2)
  const int z = bid >> 3, q = bid & 7;
  const int d = q >> 1, rh = q & 1;
  const float* P0 = R + (size_t)z * 2097152 + (d * 4 + 0) * 65536;
  const float* P1 = P0 + 65536;
  const float* P2 = P0 + 131072;
  const float* P3 = P0 + 196608;
  for (int k = threadIdx.x; k < 128 * 64; k += 256) {   // 128 dims x 64 float4
    const int dp = rh * 128 + (k >> 6), c4 = (k & 63) * 4;
    const size_t off = (size_t)dp * 256 + c4;
    float4 a = *(const float4*)(P0 + off);
    float4 b = *(const float4*)(P1 + off);
    float4 c = *(const float4*)(P2 + off);
    float4 e = *(const float4*)(P3 + off);
    ushort4 o;
    o.x = f2bf(a.x + b.x + c.x + e.x); o.y = f2bf(a.y + b.y + c.y + e.y);
    o.z = f2bf(a.z + b.z + c.z + e.z); o.w = f2bf(a.w + b.w + c.w + e.w);
    *(ushort4*)(VTb + (size_t)z * 1024 * 2048 + (size_t)(d * 256 + dp) * 2048 +
                1792 + c4) = o;
  }
}

// pv chunk classes (desc nt): m-tile, k0 (K-tiles), nt, slot (0=out,1=slot1,2=slot2)
__constant__ signed char CPM[16] = {5,5,7,7,7,6,4,4,6,6,3,3,1,2,2,0};
__constant__ signed char CPK[16] = {0,12,0,11,22,0,0,10,10,19,0,8,0,0,6,0};
__constant__ signed char CPN[16] = {12,12,11,11,10,10,10,10,9,9,8,8,8,6,6,4};
__constant__ signed char CPS[16] = {0,1,0,1,2,0,0,1,1,2,0,1,0,0,1,0};

// ---- O_b = P_b VT_b^T; slot partials now BF16 (in R_z bytes 4MB..8MB) ----
__global__ __launch_bounds__(512, 2) void pv_kernel(
    const u16* __restrict__ P, const u16* __restrict__ VTb,
    float* __restrict__ out, char* __restrict__ R) {
  __shared__ __align__(16) u16 lds[65536];
  const int cls = blockIdx.x, n = blockIdx.y;
  const size_t z = blockIdx.z;
  const int m = CPM[cls], k0 = CPK[cls], ntc = CPN[cls], sl = CPS[cls];
  const u16* Ap = P + z * 2048 * 2048 + (size_t)m * 256 * 2048 + (size_t)k0 * 64;
  const u16* Bp = VTb + z * 1024 * 2048 + (size_t)n * 256 * 2048 + (size_t)k0 * 64;
  if (sl == 0) {
    gemm_core<float, 256>(lds, Ap, Bp, out + z * 2048 * 1024, ntc,
                          2048, 2048, 1024, m * 256, n * 256);
  } else if (sl == 1) {
    // slot1 (u16) holds out rows 512..2047: base shifted by -512 rows
    u16* s1 = (u16*)(R + z * (8ul << 20) + (4ul << 20)) - (size_t)512 * 1024;
    gemm_core<u16, 256>(lds, Ap, Bp, s1, ntc, 2048, 2048, 1024, m * 256, n * 256);
  } else {
    // slot2 (u16) holds out rows 1536..2047
    u16* s2 = (u16*)(R + z * (8ul << 20) + (7ul << 20)) - (size_t)1536 * 1024;
    gemm_core<u16, 256>(lds, Ap, Bp, s2, ntc, 2048, 2048, 1024, m * 256, n * 256);
  }
}

// ---- out += slot1 (+slot2 for m>=6); bf16 slots, fixed order ----
__global__ __launch_bounds__(256) void reduce_kernel(float* __restrict__ out,
                                                     const char* __restrict__ R) {
  const int j = blockIdx.x;
  const int m = 2 + (j >> 5), z = (j >> 3) & 3, s = j & 7;
  float* ob = out + (size_t)z * 2048 * 1024;
  const u16* s1 = (const u16*)(R + (size_t)z * (8ul << 20) + (4ul << 20));
  const u16* s2 = (const u16*)(R + (size_t)z * (8ul << 20) + (7ul << 20));
  const int r0 = m * 256 + s * 32;
  for (int k = threadIdx.x; k < 32 * 256; k += 256) {   // 32 rows x 256 float4
    const int rr = r0 + (k >> 8), cc = k & 255;
    float4 o = ((float4*)(ob + (size_t)rr * 1024))[cc];
    ushort4 a = ((const ushort4*)(s1 + (size_t)(rr - 512) * 1024))[cc];
    o.x += bf2f(a.x); o.y += bf2f(a.y); o.z += bf2f(a.z); o.w += bf2f(a.w);
    if (m >= 6) {
      ushort4 b = ((const ushort4*)(s2 + (size_t)(rr - 1536) * 1024))[cc];
      o.x += bf2f(b.x); o.y += bf2f(b.y); o.z += bf2f(b.z); o.w += bf2f(b.w);
    }
    ((float4*)(ob + (size_t)rr * 1024))[cc] = o;
  }
}

extern "C" void kernel_launch(void* const* d_in, const int* in_sizes, int n_in,
                              void* d_out, int out_size, void* d_ws, size_t ws_size,
                              hipStream_t stream) {
  const float* x  = (const float*)d_in[0];
  const float* Wq = (const float*)d_in[1];
  const float* Wk = (const float*)d_in[2];
  const float* Wv = (const float*)d_in[3];
  float* out = (float*)d_out;

  char* ws = (char*)d_ws;
  u16* xb   = (u16*)(ws);                        // 16 MB  x bf16 [8192][1024]
  u16* wqb  = (u16*)(ws + (16ul << 20));         //  2 MB
  u16* wkb  = (u16*)(ws + (18ul << 20));         //  2 MB
  u16* wvb  = (u16*)(ws + (20ul << 20));         //  2 MB
  u16* Qb   = (u16*)(ws + (22ul << 20));         // 16 MB  Q bf16 [4][2048][1024]
  u16* Kb   = (u16*)(ws + (38ul << 20));         // 16 MB  K bf16
  u16* VTb  = (u16*)(ws + (54ul << 20));         // 16 MB  V^T bf16 [4][1024][2048]
  u16* Sb16 = (u16*)(ws + (70ul << 20));         // 32 MB  S/P bf16 [4][2048][2048]
  char* R   = ws + (102ul << 20);                // 32 MB  per z (8MB): vtK partials
                                                 //        f32 (0..4MB, dead after
                                                 //        vtfix) | slot1 u16 (4..7MB)
                                                 //        | slot2 u16 (7..8MB)

  cvt_all_kernel<<<11264, 256, 0, stream>>>(x, Wq, Wk, Wv, xb, wqb, wkb, wvb);

  proj_qk_kernel<<<256, 512, 0, stream>>>(xb, wqb, wkb, Qb, Kb);

  qktvt_kernel<<<256, 512, 0, stream>>>(Qb, Kb, Sb16, wvb, xb, VTb);

  smvt_kernel<<<576, 512, 0, stream>>>(Sb16, (float*)R, wvb, xb);

  vtfix_kernel<<<32, 256, 0, stream>>>((const float*)R, VTb);

  pv_kernel<<<dim3(16, 4, 4), 512, 0, stream>>>(Sb16, VTb, out, R);

  reduce_kernel<<<192, 256, 0, stream>>>(out, R);
}